// Round 6
// baseline (1973.552 us; speedup 1.0000x reference)
//
#include <hip/hip_runtime.h>

#define NNODES 100000
#define NEDGES 3200000
#define NGRAPH 1000
#define NPG    100
#define MDIM   32
#define NCDIM  10
#define NB     98          // ceil(NNODES/1024) scan blocks

// ws layout (float units):
//  xd4   @ 0        : 100000 float4  (x0,x1,x2,dinv)      1.6 MB
//  a4    @ 400000   : 100000 float4  (a0,a1,a2,dinv)      1.6 MB
//  cnt   @ 800000   : 100000 int
//  rowptr@ 900000   : 100000 int
//  cursor@ 1000000  : 100000 int
//  bsum  @ 1099000  : 128 int   | boff @ 1099128 : 128 int
//  slot  @ 1100000  : 3200000 int  (packed: r | c_local<<20)
#define WS_FLOATS 4300000   // 17.2 MB total

// ---------------- K1: in-degree histogram (int atomics) ----------------
__global__ void k_count(const int* __restrict__ col, int* __restrict__ cnt) {
    int e = blockIdx.x * blockDim.x + threadIdx.x;
    if (e < NEDGES) atomicAdd(&cnt[col[e]], 1);
}

// ---------------- K2a: per-block sums of cnt ----------------
__global__ __launch_bounds__(1024) void k_bsum(const int* __restrict__ cnt,
                                               int* __restrict__ bsum) {
    __shared__ int wsum[16];
    int b = blockIdx.x, t = threadIdx.x;
    int i = b * 1024 + t;
    int v = (i < NNODES) ? cnt[i] : 0;
    for (int off = 32; off; off >>= 1) v += __shfl_down(v, off);
    if ((t & 63) == 0) wsum[t >> 6] = v;
    __syncthreads();
    if (t < 16) {
        int s = wsum[t];
        for (int off = 8; off; off >>= 1) s += __shfl_down(s, off);
        if (t == 0) bsum[b] = s;
    }
}

// ---------------- K2b: exclusive scan of NB block sums ----------------
__global__ void k_bscan(const int* __restrict__ bsum, int* __restrict__ boff) {
    __shared__ int s[128];
    int t = threadIdx.x;
    int v = (t < NB) ? bsum[t] : 0;
    s[t] = v;
    __syncthreads();
    for (int off = 1; off < 128; off <<= 1) {
        int u = (t >= off) ? s[t - off] : 0;
        __syncthreads();
        s[t] += u;
        __syncthreads();
    }
    if (t < NB) boff[t] = s[t] - v;   // exclusive
}

// ---------------- K2c: block-local scan + offsets; also xd4/cursor ----------------
__global__ __launch_bounds__(1024) void k_scan2(const int* __restrict__ cnt,
                                                const int* __restrict__ boff,
                                                const float* __restrict__ x,
                                                int* __restrict__ rowptr,
                                                int* __restrict__ cursor,
                                                float4* __restrict__ xd4) {
    __shared__ int s[1024];
    int b = blockIdx.x, t = threadIdx.x;
    int i = b * 1024 + t;
    int c = (i < NNODES) ? cnt[i] : 0;
    s[t] = c;
    __syncthreads();
    for (int off = 1; off < 1024; off <<= 1) {
        int u = (t >= off) ? s[t - off] : 0;
        __syncthreads();
        s[t] += u;
        __syncthreads();
    }
    if (i < NNODES) {
        int excl = s[t] - c + boff[b];
        rowptr[i] = excl;
        cursor[i] = excl;
        float di = rsqrtf((float)c + 1.0f);
        xd4[i] = make_float4(x[3 * i], x[3 * i + 1], x[3 * i + 2], di);
    }
}

// ---------------- K3: scatter sources into CSR slots (pack c_local) ----------------
__global__ void k_fill(const int* __restrict__ ei, int* __restrict__ cursor,
                       int* __restrict__ slot) {
    int e = blockIdx.x * blockDim.x + threadIdx.x;
    if (e >= NEDGES) return;
    int r = ei[e];
    int c = ei[NEDGES + e];
    int cl = c - (c / NPG) * NPG;              // graph-local target index, 7 bits
    slot[atomicAdd(&cursor[c], 1)] = r | (cl << 20);
}

// ---------------- K4: a4[i] = (dinv_i*(sum_r dinv_r x_r + dinv_i x_i), dinv_i) ------
__global__ void k_a(const int* __restrict__ rowptr, const int* __restrict__ cnt,
                    const int* __restrict__ slot, const float4* __restrict__ xd4,
                    float4* __restrict__ a4) {
    int i = blockIdx.x * blockDim.x + threadIdx.x;
    if (i >= NNODES) return;
    int s = rowptr[i], d = cnt[i];
    float ax = 0.f, ay = 0.f, az = 0.f;
    for (int k = 0; k < d; ++k) {
        int r = slot[s + k] & 0xFFFFF;
        float4 xr = xd4[r];
        ax += xr.w * xr.x; ay += xr.w * xr.y; az += xr.w * xr.z;
    }
    float4 xi = xd4[i];
    float di = xi.w;
    a4[i] = make_float4(di * (ax + di * xi.x),
                        di * (ay + di * xi.y),
                        di * (az + di * xi.z), di);
}

// ---------------- K5: fused per-graph, edge-parallel with LDS accumulation ---------
__global__ __launch_bounds__(256) void k_fused(
    const int* __restrict__ rowptr, const int* __restrict__ slot,
    const float4* __restrict__ a4, const float* __restrict__ mv,
    const float* __restrict__ W1, const float* __restrict__ b1,
    const float* __restrict__ W2, const float* __restrict__ b2,
    const float* __restrict__ Wc1, const float* __restrict__ bc1,
    const float* __restrict__ Wc2, const float* __restrict__ bc2,
    float* __restrict__ out)
{
    __shared__ float  W2s[64 * 128];      // 32 KB
    __shared__ float  aggh[NPG * 65];     // 26 KB, pad 65 for bank spread
    __shared__ float4 W14[64];            // (W1 col, b1)
    __shared__ float  pools[4 * 128];
    __shared__ float  zbuf[160];
    __shared__ float  zz[64];

    int g = blockIdx.x;
    int t = threadIdx.x;
    int w = t >> 6;
    int lane = t & 63;

    for (int k = t; k < 2048; k += 256)
        ((float4*)W2s)[k] = ((const float4*)W2)[k];
    if (t < 64) W14[t] = make_float4(W1[t], W1[64 + t], W1[128 + t], b1[t]);
    for (int k = t; k < NPG * 65; k += 256) aggh[k] = 0.f;
    int lo = rowptr[g * NPG];
    int hi = (g == NGRAPH - 1) ? NEDGES : rowptr[(g + 1) * NPG];
    __syncthreads();

    // ---- phase 1: edge-parallel aggregation into LDS (unroll x2 for MLP) ----
    for (int s0 = lo + t; s0 < hi; s0 += 512) {
        int s1 = s0 + 256;
        bool has1 = s1 < hi;
        int pk0 = slot[s0];
        int pk1 = has1 ? slot[s1] : pk0;
        float4 ar0 = a4[pk0 & 0xFFFFF];
        float4 ar1 = a4[pk1 & 0xFFFFF];
        int c0 = pk0 >> 20, c1 = pk1 >> 20;
        float w0 = ar0.w;
        float w1v = has1 ? ar1.w : 0.f;
        float* row0 = &aggh[c0 * 65];
        float* row1 = &aggh[c1 * 65];
        #pragma unroll
        for (int f = 0; f < 64; ++f) {
            float4 wf = W14[f];
            float h0 = fmaxf(ar0.x * wf.x + ar0.y * wf.y + ar0.z * wf.z + wf.w, 0.f);
            float h1 = fmaxf(ar1.x * wf.x + ar1.y * wf.y + ar1.z * wf.z + wf.w, 0.f);
            atomicAdd(&row0[f], w0 * h0);
            atomicAdd(&row1[f], w1v * h1);
        }
    }
    __syncthreads();

    // ---- phase 1.5: self-loop term + final dinv_c scaling ----
    for (int idx = t; idx < NPG * 64; idx += 256) {
        int n = idx >> 6, f = idx & 63;
        float4 ai = a4[g * NPG + n];
        float4 wf = W14[f];
        float h = fmaxf(ai.x * wf.x + ai.y * wf.y + ai.z * wf.z + wf.w, 0.f);
        aggh[n * 65 + f] = ai.w * (aggh[n * 65 + f] + ai.w * h);
    }
    __syncthreads();

    // ---- phase 2: [100][64] @ [64][128] + relu + mean-pool ----
    float2 b2v = *(const float2*)&b2[2 * lane];
    float pool0 = 0.f, pool1 = 0.f;
    for (int n = w; n < NPG; n += 4) {
        float v0 = b2v.x, v1 = b2v.y;
        #pragma unroll
        for (int f = 0; f < 64; ++f) {
            float rv = aggh[n * 65 + f];                       // broadcast
            float2 wv = *(float2*)&W2s[f * 128 + 2 * lane];    // ds_read_b64
            v0 += rv * wv.x;
            v1 += rv * wv.y;
        }
        pool0 += fmaxf(v0, 0.f);
        pool1 += fmaxf(v1, 0.f);
    }
    pools[w * 128 + 2 * lane]     = pool0;
    pools[w * 128 + 2 * lane + 1] = pool1;
    __syncthreads();
    if (t < 128) {
        zbuf[t] = (pools[t] + pools[128 + t] + pools[256 + t] + pools[384 + t]) * (1.0f / NPG);
    }
    if (t < MDIM) zbuf[128 + t] = mv[g * MDIM + t];
    __syncthreads();
    if (t < 64) {
        float v = bc1[t];
        for (int k = 0; k < 160; ++k) v += zbuf[k] * Wc1[k * 64 + t];
        zz[t] = fmaxf(v, 0.f);
    }
    __syncthreads();
    if (t < NCDIM) {
        float o = bc2[t];
        #pragma unroll
        for (int k = 0; k < 64; ++k) o += zz[k] * Wc2[k * NCDIM + t];
        out[g * NCDIM + t] = o;
    }
}

extern "C" void kernel_launch(void* const* d_in, const int* in_sizes, int n_in,
                              void* d_out, int out_size, void* d_ws, size_t ws_size,
                              hipStream_t stream) {
    const float* x   = (const float*)d_in[0];
    const int*   ei  = (const int*)d_in[1];   // int64 in ref -> int32 on device
    const float* mv  = (const float*)d_in[3];
    const float* W1  = (const float*)d_in[4];
    const float* b1  = (const float*)d_in[5];
    const float* W2  = (const float*)d_in[6];
    const float* b2  = (const float*)d_in[7];
    const float* Wc1 = (const float*)d_in[8];
    const float* bc1 = (const float*)d_in[9];
    const float* Wc2 = (const float*)d_in[10];
    const float* bc2 = (const float*)d_in[11];
    float* out = (float*)d_out;

    if (ws_size < (size_t)WS_FLOATS * sizeof(float)) return;  // clean fail, no fault

    float*  ws     = (float*)d_ws;
    float4* xd4    = (float4*)(ws);             // 100000 float4
    float4* a4     = (float4*)(ws + 400000);    // 100000 float4
    int*    cnt    = (int*)(ws + 800000);
    int*    rowptr = (int*)(ws + 900000);
    int*    cursor = (int*)(ws + 1000000);
    int*    bsum   = (int*)(ws + 1099000);      // 128 ints
    int*    boff   = (int*)(ws + 1099128);      // 128 ints
    int*    slot   = (int*)(ws + 1100000);      // 3200000 ints

    hipMemsetAsync(cnt, 0, (size_t)NNODES * sizeof(int), stream);

    const int* col = ei + NEDGES;

    k_count<<<(NEDGES + 255) / 256, 256, 0, stream>>>(col, cnt);
    k_bsum <<<NB, 1024, 0, stream>>>(cnt, bsum);
    k_bscan<<<1, 128, 0, stream>>>(bsum, boff);
    k_scan2<<<NB, 1024, 0, stream>>>(cnt, boff, x, rowptr, cursor, xd4);
    k_fill <<<(NEDGES + 255) / 256, 256, 0, stream>>>(ei, cursor, slot);
    k_a    <<<(NNODES + 255) / 256, 256, 0, stream>>>(rowptr, cnt, slot, xd4, a4);
    k_fused<<<NGRAPH, 256, 0, stream>>>(rowptr, slot, a4, mv,
                                        W1, b1, W2, b2, Wc1, bc1, Wc2, bc2, out);
}

// Round 7
// 664.451 us; speedup vs baseline: 2.9702x; 2.9702x over previous
//
#include <hip/hip_runtime.h>

#define NNODES 100000
#define NEDGES 3200000
#define NGRAPH 1000
#define NPG    100
#define MDIM   32
#define NCDIM  10
#define NB     98          // ceil(NNODES/1024) scan blocks

// ws layout (float units):
//  xd4   @ 0        : 100000 float4  (x0,x1,x2,dinv)      1.6 MB
//  a4    @ 400000   : 100000 float4  (a0,a1,a2,dinv)      1.6 MB
//  cnt   @ 800000   : 100000 int
//  rowptr@ 900000   : 100000 int
//  cursor@ 1000000  : 100000 int
//  bsum  @ 1099000  : 128 int   | boff @ 1099128 : 128 int
//  slot  @ 1100000  : 3200000 int
#define WS_FLOATS 4300000   // 17.2 MB total

// ---------------- K1: in-degree histogram (int atomics) ----------------
__global__ void k_count(const int* __restrict__ col, int* __restrict__ cnt) {
    int e = blockIdx.x * blockDim.x + threadIdx.x;
    if (e < NEDGES) atomicAdd(&cnt[col[e]], 1);
}

// ---------------- K2a: per-block sums of cnt ----------------
__global__ __launch_bounds__(1024) void k_bsum(const int* __restrict__ cnt,
                                               int* __restrict__ bsum) {
    __shared__ int wsum[16];
    int b = blockIdx.x, t = threadIdx.x;
    int i = b * 1024 + t;
    int v = (i < NNODES) ? cnt[i] : 0;
    for (int off = 32; off; off >>= 1) v += __shfl_down(v, off);
    if ((t & 63) == 0) wsum[t >> 6] = v;
    __syncthreads();
    if (t < 16) {
        int s = wsum[t];
        for (int off = 8; off; off >>= 1) s += __shfl_down(s, off);
        if (t == 0) bsum[b] = s;
    }
}

// ---------------- K2b: exclusive scan of NB block sums ----------------
__global__ void k_bscan(const int* __restrict__ bsum, int* __restrict__ boff) {
    __shared__ int s[128];
    int t = threadIdx.x;
    int v = (t < NB) ? bsum[t] : 0;
    s[t] = v;
    __syncthreads();
    for (int off = 1; off < 128; off <<= 1) {
        int u = (t >= off) ? s[t - off] : 0;
        __syncthreads();
        s[t] += u;
        __syncthreads();
    }
    if (t < NB) boff[t] = s[t] - v;   // exclusive
}

// ---------------- K2c: block-local scan + offsets; also xd4/cursor ----------------
__global__ __launch_bounds__(1024) void k_scan2(const int* __restrict__ cnt,
                                                const int* __restrict__ boff,
                                                const float* __restrict__ x,
                                                int* __restrict__ rowptr,
                                                int* __restrict__ cursor,
                                                float4* __restrict__ xd4) {
    __shared__ int s[1024];
    int b = blockIdx.x, t = threadIdx.x;
    int i = b * 1024 + t;
    int c = (i < NNODES) ? cnt[i] : 0;
    s[t] = c;
    __syncthreads();
    for (int off = 1; off < 1024; off <<= 1) {
        int u = (t >= off) ? s[t - off] : 0;
        __syncthreads();
        s[t] += u;
        __syncthreads();
    }
    if (i < NNODES) {
        int excl = s[t] - c + boff[b];
        rowptr[i] = excl;
        cursor[i] = excl;
        float di = rsqrtf((float)c + 1.0f);
        xd4[i] = make_float4(x[3 * i], x[3 * i + 1], x[3 * i + 2], di);
    }
}

// ---------------- K3: scatter sources into CSR slots ----------------
__global__ void k_fill(const int* __restrict__ ei, int* __restrict__ cursor,
                       int* __restrict__ slot) {
    int e = blockIdx.x * blockDim.x + threadIdx.x;
    if (e >= NEDGES) return;
    int r = ei[e];
    int c = ei[NEDGES + e];
    slot[atomicAdd(&cursor[c], 1)] = r;
}

// ---------------- K4: a4[i] = (dinv_i*(sum_r dinv_r x_r + dinv_i x_i), dinv_i) ------
__global__ void k_a(const int* __restrict__ rowptr, const int* __restrict__ cnt,
                    const int* __restrict__ slot, const float4* __restrict__ xd4,
                    float4* __restrict__ a4) {
    int i = blockIdx.x * blockDim.x + threadIdx.x;
    if (i >= NNODES) return;
    int s = rowptr[i], d = cnt[i];
    float ax = 0.f, ay = 0.f, az = 0.f;
    for (int k = 0; k < d; ++k) {
        int r = slot[s + k];
        float4 xr = xd4[r];
        ax += xr.w * xr.x; ay += xr.w * xr.y; az += xr.w * xr.z;
    }
    float4 xi = xd4[i];
    float di = xi.w;
    a4[i] = make_float4(di * (ax + di * xi.x),
                        di * (ay + di * xi.y),
                        di * (az + di * xi.z), di);
}

// ---------------- K5: fused per-graph; wave-per-node, 8-deep gather pipeline -------
__global__ __launch_bounds__(256) void k_fused(
    const int* __restrict__ rowptr, const int* __restrict__ cnt,
    const int* __restrict__ slot, const float4* __restrict__ a4,
    const float* __restrict__ mv,
    const float* __restrict__ W1, const float* __restrict__ b1,
    const float* __restrict__ W2, const float* __restrict__ b2,
    const float* __restrict__ Wc1, const float* __restrict__ bc1,
    const float* __restrict__ Wc2, const float* __restrict__ bc2,
    float* __restrict__ out)
{
    __shared__ float W2s[64 * 128];          // 32 KB
    __shared__ float rowbuf[4][64];
    __shared__ float pools[4 * 128];
    __shared__ float zbuf[160];
    __shared__ float zz[64];

    int g = blockIdx.x;
    int t = threadIdx.x;
    int w = t >> 6;            // wave 0..3
    int lane = t & 63;         // = feature f (phase 1) / output pair (phase 2)

    for (int k = t; k < 2048; k += 256)
        ((float4*)W2s)[k] = ((const float4*)W2)[k];
    float w10 = W1[lane], w11 = W1[64 + lane], w12 = W1[128 + lane], b1f = b1[lane];
    float2 b2v = *(const float2*)&b2[2 * lane];
    float pool0 = 0.f, pool1 = 0.f;
    __syncthreads();

    for (int n = w; n < NPG; n += 4) {
        int node = g * NPG + n;
        int s = rowptr[node], d = cnt[node];
        float acc = 0.f;
        for (int base = 0; base < d; base += 64) {
            int m = min(64, d - base);                         // m >= 1
            int sl = (lane < m) ? slot[s + base + lane] : 0;   // coalesced
            for (int k0 = 0; k0 < m; k0 += 8) {
                float4 pre[8];
                #pragma unroll
                for (int j = 0; j < 8; ++j) {
                    int kk = min(k0 + j, m - 1);
                    pre[j] = a4[__shfl(sl, kk)];               // 8 independent loads
                }
                #pragma unroll
                for (int j = 0; j < 8; ++j) {
                    if (k0 + j < m) {                          // wave-uniform
                        float4 ar = pre[j];
                        float h = fmaxf(ar.x * w10 + ar.y * w11 + ar.z * w12 + b1f, 0.f);
                        acc += ar.w * h;
                    }
                }
            }
        }
        float4 ai = a4[node];
        float hs = fmaxf(ai.x * w10 + ai.y * w11 + ai.z * w12 + b1f, 0.f);
        rowbuf[w][lane] = ai.w * (acc + ai.w * hs);
        // same-wave LDS write->read; compiler inserts lgkmcnt wait
        float v0 = b2v.x, v1 = b2v.y;
        #pragma unroll
        for (int f = 0; f < 64; ++f) {
            float rv = rowbuf[w][f];                           // broadcast
            float2 wv = *(float2*)&W2s[f * 128 + 2 * lane];    // ds_read_b64
            v0 += rv * wv.x;
            v1 += rv * wv.y;
        }
        pool0 += fmaxf(v0, 0.f);
        pool1 += fmaxf(v1, 0.f);
    }
    pools[w * 128 + 2 * lane]     = pool0;
    pools[w * 128 + 2 * lane + 1] = pool1;
    __syncthreads();
    if (t < 128) {
        zbuf[t] = (pools[t] + pools[128 + t] + pools[256 + t] + pools[384 + t]) * (1.0f / NPG);
    }
    if (t < MDIM) zbuf[128 + t] = mv[g * MDIM + t];
    __syncthreads();
    if (t < 64) {
        float v = bc1[t];
        for (int k = 0; k < 160; ++k) v += zbuf[k] * Wc1[k * 64 + t];
        zz[t] = fmaxf(v, 0.f);
    }
    __syncthreads();
    if (t < NCDIM) {
        float o = bc2[t];
        #pragma unroll
        for (int k = 0; k < 64; ++k) o += zz[k] * Wc2[k * NCDIM + t];
        out[g * NCDIM + t] = o;
    }
}

extern "C" void kernel_launch(void* const* d_in, const int* in_sizes, int n_in,
                              void* d_out, int out_size, void* d_ws, size_t ws_size,
                              hipStream_t stream) {
    const float* x   = (const float*)d_in[0];
    const int*   ei  = (const int*)d_in[1];   // int64 in ref -> int32 on device
    const float* mv  = (const float*)d_in[3];
    const float* W1  = (const float*)d_in[4];
    const float* b1  = (const float*)d_in[5];
    const float* W2  = (const float*)d_in[6];
    const float* b2  = (const float*)d_in[7];
    const float* Wc1 = (const float*)d_in[8];
    const float* bc1 = (const float*)d_in[9];
    const float* Wc2 = (const float*)d_in[10];
    const float* bc2 = (const float*)d_in[11];
    float* out = (float*)d_out;

    if (ws_size < (size_t)WS_FLOATS * sizeof(float)) return;  // clean fail, no fault

    float*  ws     = (float*)d_ws;
    float4* xd4    = (float4*)(ws);             // 100000 float4
    float4* a4     = (float4*)(ws + 400000);    // 100000 float4
    int*    cnt    = (int*)(ws + 800000);
    int*    rowptr = (int*)(ws + 900000);
    int*    cursor = (int*)(ws + 1000000);
    int*    bsum   = (int*)(ws + 1099000);      // 128 ints
    int*    boff   = (int*)(ws + 1099128);      // 128 ints
    int*    slot   = (int*)(ws + 1100000);      // 3200000 ints

    hipMemsetAsync(cnt, 0, (size_t)NNODES * sizeof(int), stream);

    const int* col = ei + NEDGES;

    k_count<<<(NEDGES + 255) / 256, 256, 0, stream>>>(col, cnt);
    k_bsum <<<NB, 1024, 0, stream>>>(cnt, bsum);
    k_bscan<<<1, 128, 0, stream>>>(bsum, boff);
    k_scan2<<<NB, 1024, 0, stream>>>(cnt, boff, x, rowptr, cursor, xd4);
    k_fill <<<(NEDGES + 255) / 256, 256, 0, stream>>>(ei, cursor, slot);
    k_a    <<<(NNODES + 255) / 256, 256, 0, stream>>>(rowptr, cnt, slot, xd4, a4);
    k_fused<<<NGRAPH, 256, 0, stream>>>(rowptr, cnt, slot, a4, mv,
                                        W1, b1, W2, b2, Wc1, bc1, Wc2, bc2, out);
}

// Round 8
// 542.683 us; speedup vs baseline: 3.6367x; 1.2244x over previous
//
#include <hip/hip_runtime.h>

#define NNODES 100000
#define NEDGES 3200000
#define NGRAPH 1000
#define NPG    100
#define MDIM   32
#define NCDIM  10
#define NB     98          // ceil(NNODES/1024) scan blocks

#define NPART   8          // scatter partitions (== XCD count)
#define PSIZE   12500      // nodes per partition
#define FCHUNK  6250       // edges per fill chunk
#define FBLKS   (NEDGES / FCHUNK)   // 512 chunks

// ws layout (float units):
//  xd4   @ 0        : 100000 float4  (x0,x1,x2,dinv)      1.6 MB
//  a4    @ 400000   : 100000 float4  (a0,a1,a2,dinv)      1.6 MB
//  cnt   @ 800000   : 100000 int
//  rowptr@ 900000   : 100000 int
//  cursor@ 1000000  : 100000 int
//  bsum  @ 1099000  : 128 int   | boff @ 1099128 : 128 int
//  slot  @ 1100000  : 3200000 int
#define WS_FLOATS 4300000   // 17.2 MB total

// ---------------- K1: in-degree histogram (int atomics) ----------------
__global__ void k_count(const int* __restrict__ col, int* __restrict__ cnt) {
    int e = blockIdx.x * blockDim.x + threadIdx.x;
    if (e < NEDGES) atomicAdd(&cnt[col[e]], 1);
}

// ---------------- K2a: per-block sums of cnt ----------------
__global__ __launch_bounds__(1024) void k_bsum(const int* __restrict__ cnt,
                                               int* __restrict__ bsum) {
    __shared__ int wsum[16];
    int b = blockIdx.x, t = threadIdx.x;
    int i = b * 1024 + t;
    int v = (i < NNODES) ? cnt[i] : 0;
    for (int off = 32; off; off >>= 1) v += __shfl_down(v, off);
    if ((t & 63) == 0) wsum[t >> 6] = v;
    __syncthreads();
    if (t < 16) {
        int s = wsum[t];
        for (int off = 8; off; off >>= 1) s += __shfl_down(s, off);
        if (t == 0) bsum[b] = s;
    }
}

// ---------------- K2b: exclusive scan of NB block sums ----------------
__global__ void k_bscan(const int* __restrict__ bsum, int* __restrict__ boff) {
    __shared__ int s[128];
    int t = threadIdx.x;
    int v = (t < NB) ? bsum[t] : 0;
    s[t] = v;
    __syncthreads();
    for (int off = 1; off < 128; off <<= 1) {
        int u = (t >= off) ? s[t - off] : 0;
        __syncthreads();
        s[t] += u;
        __syncthreads();
    }
    if (t < NB) boff[t] = s[t] - v;   // exclusive
}

// ---------------- K2c: block-local scan + offsets; also xd4/cursor ----------------
__global__ __launch_bounds__(1024) void k_scan2(const int* __restrict__ cnt,
                                                const int* __restrict__ boff,
                                                const float* __restrict__ x,
                                                int* __restrict__ rowptr,
                                                int* __restrict__ cursor,
                                                float4* __restrict__ xd4) {
    __shared__ int s[1024];
    int b = blockIdx.x, t = threadIdx.x;
    int i = b * 1024 + t;
    int c = (i < NNODES) ? cnt[i] : 0;
    s[t] = c;
    __syncthreads();
    for (int off = 1; off < 1024; off <<= 1) {
        int u = (t >= off) ? s[t - off] : 0;
        __syncthreads();
        s[t] += u;
        __syncthreads();
    }
    if (i < NNODES) {
        int excl = s[t] - c + boff[b];
        rowptr[i] = excl;
        cursor[i] = excl;
        float di = rsqrtf((float)c + 1.0f);
        xd4[i] = make_float4(x[3 * i], x[3 * i + 1], x[3 * i + 2], di);
    }
}

// ---------------- K3: XCD-partitioned scatter into CSR slots ----------------
// part = blockIdx % 8 -> (empirically) fixed XCD; each partition's slot/cursor
// region is then written by a single XCD's L2, killing line ping-pong.
// Correct regardless of the blockIdx->XCD mapping (only locality depends on it).
__global__ __launch_bounds__(256) void k_fill(const int* __restrict__ ei,
                                              int* __restrict__ cursor,
                                              int* __restrict__ slot) {
    int part  = blockIdx.x & (NPART - 1);
    int chunk = blockIdx.x >> 3;
    int base  = chunk * FCHUNK;
    int end   = base + FCHUNK;
    int clo   = part * PSIZE;
    int chi   = clo + PSIZE;
    for (int e = base + threadIdx.x; e < end; e += 256) {
        int c = ei[NEDGES + e];
        if (c >= clo && c < chi) {
            int r = ei[e];
            slot[atomicAdd(&cursor[c], 1)] = r;
        }
    }
}

// ---------------- K4: a4[i] = (dinv_i*(sum_r dinv_r x_r + dinv_i x_i), dinv_i) ------
__global__ void k_a(const int* __restrict__ rowptr, const int* __restrict__ cnt,
                    const int* __restrict__ slot, const float4* __restrict__ xd4,
                    float4* __restrict__ a4) {
    int i = blockIdx.x * blockDim.x + threadIdx.x;
    if (i >= NNODES) return;
    int s = rowptr[i], d = cnt[i];
    float ax = 0.f, ay = 0.f, az = 0.f;
    for (int k = 0; k < d; ++k) {
        int r = slot[s + k];
        float4 xr = xd4[r];
        ax += xr.w * xr.x; ay += xr.w * xr.y; az += xr.w * xr.z;
    }
    float4 xi = xd4[i];
    float di = xi.w;
    a4[i] = make_float4(di * (ax + di * xi.x),
                        di * (ay + di * xi.y),
                        di * (az + di * xi.z), di);
}

// ---------------- K5: fused per-graph; wave-per-node, 8-deep gather pipeline -------
__global__ __launch_bounds__(256) void k_fused(
    const int* __restrict__ rowptr, const int* __restrict__ cnt,
    const int* __restrict__ slot, const float4* __restrict__ a4,
    const float* __restrict__ mv,
    const float* __restrict__ W1, const float* __restrict__ b1,
    const float* __restrict__ W2, const float* __restrict__ b2,
    const float* __restrict__ Wc1, const float* __restrict__ bc1,
    const float* __restrict__ Wc2, const float* __restrict__ bc2,
    float* __restrict__ out)
{
    __shared__ float W2s[64 * 128];          // 32 KB
    __shared__ float rowbuf[4][64];
    __shared__ float pools[4 * 128];
    __shared__ float zbuf[160];
    __shared__ float zz[64];

    int g = blockIdx.x;
    int t = threadIdx.x;
    int w = t >> 6;            // wave 0..3
    int lane = t & 63;         // = feature f (phase 1) / output pair (phase 2)

    for (int k = t; k < 2048; k += 256)
        ((float4*)W2s)[k] = ((const float4*)W2)[k];
    float w10 = W1[lane], w11 = W1[64 + lane], w12 = W1[128 + lane], b1f = b1[lane];
    float2 b2v = *(const float2*)&b2[2 * lane];
    float pool0 = 0.f, pool1 = 0.f;
    __syncthreads();

    for (int n = w; n < NPG; n += 4) {
        int node = g * NPG + n;
        int s = rowptr[node], d = cnt[node];
        float acc = 0.f;
        for (int base = 0; base < d; base += 64) {
            int m = min(64, d - base);                         // m >= 1
            int sl = (lane < m) ? slot[s + base + lane] : 0;   // coalesced
            for (int k0 = 0; k0 < m; k0 += 8) {
                float4 pre[8];
                #pragma unroll
                for (int j = 0; j < 8; ++j) {
                    int kk = min(k0 + j, m - 1);
                    pre[j] = a4[__shfl(sl, kk)];               // 8 independent loads
                }
                #pragma unroll
                for (int j = 0; j < 8; ++j) {
                    if (k0 + j < m) {                          // wave-uniform
                        float4 ar = pre[j];
                        float h = fmaxf(ar.x * w10 + ar.y * w11 + ar.z * w12 + b1f, 0.f);
                        acc += ar.w * h;
                    }
                }
            }
        }
        float4 ai = a4[node];
        float hs = fmaxf(ai.x * w10 + ai.y * w11 + ai.z * w12 + b1f, 0.f);
        rowbuf[w][lane] = ai.w * (acc + ai.w * hs);
        // same-wave LDS write->read; compiler inserts lgkmcnt wait
        float v0 = b2v.x, v1 = b2v.y;
        #pragma unroll
        for (int f = 0; f < 64; ++f) {
            float rv = rowbuf[w][f];                           // broadcast
            float2 wv = *(float2*)&W2s[f * 128 + 2 * lane];    // ds_read_b64
            v0 += rv * wv.x;
            v1 += rv * wv.y;
        }
        pool0 += fmaxf(v0, 0.f);
        pool1 += fmaxf(v1, 0.f);
    }
    pools[w * 128 + 2 * lane]     = pool0;
    pools[w * 128 + 2 * lane + 1] = pool1;
    __syncthreads();
    if (t < 128) {
        zbuf[t] = (pools[t] + pools[128 + t] + pools[256 + t] + pools[384 + t]) * (1.0f / NPG);
    }
    if (t < MDIM) zbuf[128 + t] = mv[g * MDIM + t];
    __syncthreads();
    if (t < 64) {
        float v = bc1[t];
        for (int k = 0; k < 160; ++k) v += zbuf[k] * Wc1[k * 64 + t];
        zz[t] = fmaxf(v, 0.f);
    }
    __syncthreads();
    if (t < NCDIM) {
        float o = bc2[t];
        #pragma unroll
        for (int k = 0; k < 64; ++k) o += zz[k] * Wc2[k * NCDIM + t];
        out[g * NCDIM + t] = o;
    }
}

extern "C" void kernel_launch(void* const* d_in, const int* in_sizes, int n_in,
                              void* d_out, int out_size, void* d_ws, size_t ws_size,
                              hipStream_t stream) {
    const float* x   = (const float*)d_in[0];
    const int*   ei  = (const int*)d_in[1];   // int64 in ref -> int32 on device
    const float* mv  = (const float*)d_in[3];
    const float* W1  = (const float*)d_in[4];
    const float* b1  = (const float*)d_in[5];
    const float* W2  = (const float*)d_in[6];
    const float* b2  = (const float*)d_in[7];
    const float* Wc1 = (const float*)d_in[8];
    const float* bc1 = (const float*)d_in[9];
    const float* Wc2 = (const float*)d_in[10];
    const float* bc2 = (const float*)d_in[11];
    float* out = (float*)d_out;

    if (ws_size < (size_t)WS_FLOATS * sizeof(float)) return;  // clean fail, no fault

    float*  ws     = (float*)d_ws;
    float4* xd4    = (float4*)(ws);             // 100000 float4
    float4* a4     = (float4*)(ws + 400000);    // 100000 float4
    int*    cnt    = (int*)(ws + 800000);
    int*    rowptr = (int*)(ws + 900000);
    int*    cursor = (int*)(ws + 1000000);
    int*    bsum   = (int*)(ws + 1099000);      // 128 ints
    int*    boff   = (int*)(ws + 1099128);      // 128 ints
    int*    slot   = (int*)(ws + 1100000);      // 3200000 ints

    hipMemsetAsync(cnt, 0, (size_t)NNODES * sizeof(int), stream);

    const int* col = ei + NEDGES;

    k_count<<<(NEDGES + 255) / 256, 256, 0, stream>>>(col, cnt);
    k_bsum <<<NB, 1024, 0, stream>>>(cnt, bsum);
    k_bscan<<<1, 128, 0, stream>>>(bsum, boff);
    k_scan2<<<NB, 1024, 0, stream>>>(cnt, boff, x, rowptr, cursor, xd4);
    k_fill <<<FBLKS * NPART, 256, 0, stream>>>(ei, cursor, slot);
    k_a    <<<(NNODES + 255) / 256, 256, 0, stream>>>(rowptr, cnt, slot, xd4, a4);
    k_fused<<<NGRAPH, 256, 0, stream>>>(rowptr, cnt, slot, a4, mv,
                                        W1, b1, W2, b2, Wc1, bc1, Wc2, bc2, out);
}

// Round 9
// 496.233 us; speedup vs baseline: 3.9771x; 1.0936x over previous
//
#include <hip/hip_runtime.h>

#define NNODES 100000
#define NEDGES 3200000
#define NGRAPH 1000
#define NPG    100
#define MDIM   32
#define NCDIM  10
#define NB     98          // ceil(NNODES/1024) scan blocks

#define NPART   8          // scatter partitions (== XCD count)
#define PSIZE   12500      // nodes per partition
#define FCHUNK  6250       // edges per chunk
#define FBLKS   (NEDGES / FCHUNK)   // 512 chunks

// ws layout (float units):
//  xd4   @ 0        : 100000 float4  (x0,x1,x2,dinv)      1.6 MB
//  a4    @ 400000   : 100000 float4  (a0,a1,a2,dinv)      1.6 MB
//  cnt   @ 800000   : 100000 int
//  rowptr@ 900000   : 100000 int
//  cursor@ 1000000  : 100000 int
//  bsum  @ 1099000  : 128 int   | boff @ 1099128 : 128 int
//  slot  @ 1100000  : 3200000 int
#define WS_FLOATS 4300000   // 17.2 MB total

// ---------------- K1: in-degree histogram, XCD-partitioned ----------------
__global__ __launch_bounds__(256) void k_count(const int* __restrict__ col,
                                               int* __restrict__ cnt) {
    int part  = blockIdx.x & (NPART - 1);
    int chunk = blockIdx.x >> 3;
    int base  = chunk * FCHUNK;
    int end   = base + FCHUNK;
    int clo   = part * PSIZE;
    int chi   = clo + PSIZE;
    for (int e = base + threadIdx.x; e < end; e += 256) {
        int c = col[e];
        if (c >= clo && c < chi) atomicAdd(&cnt[c], 1);
    }
}

// ---------------- K2a: per-block sums of cnt ----------------
__global__ __launch_bounds__(1024) void k_bsum(const int* __restrict__ cnt,
                                               int* __restrict__ bsum) {
    __shared__ int wsum[16];
    int b = blockIdx.x, t = threadIdx.x;
    int i = b * 1024 + t;
    int v = (i < NNODES) ? cnt[i] : 0;
    for (int off = 32; off; off >>= 1) v += __shfl_down(v, off);
    if ((t & 63) == 0) wsum[t >> 6] = v;
    __syncthreads();
    if (t < 16) {
        int s = wsum[t];
        for (int off = 8; off; off >>= 1) s += __shfl_down(s, off);
        if (t == 0) bsum[b] = s;
    }
}

// ---------------- K2b: exclusive scan of NB block sums ----------------
__global__ void k_bscan(const int* __restrict__ bsum, int* __restrict__ boff) {
    __shared__ int s[128];
    int t = threadIdx.x;
    int v = (t < NB) ? bsum[t] : 0;
    s[t] = v;
    __syncthreads();
    for (int off = 1; off < 128; off <<= 1) {
        int u = (t >= off) ? s[t - off] : 0;
        __syncthreads();
        s[t] += u;
        __syncthreads();
    }
    if (t < NB) boff[t] = s[t] - v;   // exclusive
}

// ---------------- K2c: block-local scan + offsets; also xd4/cursor ----------------
__global__ __launch_bounds__(1024) void k_scan2(const int* __restrict__ cnt,
                                                const int* __restrict__ boff,
                                                const float* __restrict__ x,
                                                int* __restrict__ rowptr,
                                                int* __restrict__ cursor,
                                                float4* __restrict__ xd4) {
    __shared__ int s[1024];
    int b = blockIdx.x, t = threadIdx.x;
    int i = b * 1024 + t;
    int c = (i < NNODES) ? cnt[i] : 0;
    s[t] = c;
    __syncthreads();
    for (int off = 1; off < 1024; off <<= 1) {
        int u = (t >= off) ? s[t - off] : 0;
        __syncthreads();
        s[t] += u;
        __syncthreads();
    }
    if (i < NNODES) {
        int excl = s[t] - c + boff[b];
        rowptr[i] = excl;
        cursor[i] = excl;
        float di = rsqrtf((float)c + 1.0f);
        xd4[i] = make_float4(x[3 * i], x[3 * i + 1], x[3 * i + 2], di);
    }
}

// ---------------- K3: XCD-partitioned scatter into CSR slots ----------------
__global__ __launch_bounds__(256) void k_fill(const int* __restrict__ ei,
                                              int* __restrict__ cursor,
                                              int* __restrict__ slot) {
    int part  = blockIdx.x & (NPART - 1);
    int chunk = blockIdx.x >> 3;
    int base  = chunk * FCHUNK;
    int end   = base + FCHUNK;
    int clo   = part * PSIZE;
    int chi   = clo + PSIZE;
    for (int e = base + threadIdx.x; e < end; e += 256) {
        int c = ei[NEDGES + e];
        if (c >= clo && c < chi) {
            int r = ei[e];
            slot[atomicAdd(&cursor[c], 1)] = r;
        }
    }
}

// ---------------- K4: a4[i] = (dinv_i*(sum_r dinv_r x_r + dinv_i x_i), dinv_i) ------
__global__ void k_a(const int* __restrict__ rowptr, const int* __restrict__ cnt,
                    const int* __restrict__ slot, const float4* __restrict__ xd4,
                    float4* __restrict__ a4) {
    int i = blockIdx.x * blockDim.x + threadIdx.x;
    if (i >= NNODES) return;
    int s = rowptr[i], d = cnt[i];
    float ax = 0.f, ay = 0.f, az = 0.f;
    for (int k = 0; k < d; ++k) {
        int r = slot[s + k];
        float4 xr = xd4[r];
        ax += xr.w * xr.x; ay += xr.w * xr.y; az += xr.w * xr.z;
    }
    float4 xi = xd4[i];
    float di = xi.w;
    a4[i] = make_float4(di * (ax + di * xi.x),
                        di * (ay + di * xi.y),
                        di * (az + di * xi.z), di);
}

// ---------------- K5: fused per-graph; reg-blocked phase 2, W2 from global ---------
__global__ __launch_bounds__(256, 4) void k_fused(
    const int* __restrict__ rowptr, const int* __restrict__ cnt,
    const int* __restrict__ slot, const float4* __restrict__ a4,
    const float* __restrict__ mv,
    const float* __restrict__ W1, const float* __restrict__ b1,
    const float* __restrict__ W2, const float* __restrict__ b2,
    const float* __restrict__ Wc1, const float* __restrict__ bc1,
    const float* __restrict__ Wc2, const float* __restrict__ bc2,
    float* __restrict__ out)
{
    __shared__ float aggh[NPG * 65];   // 26 KB; row n = h2-input row of node n
    __shared__ float pools[4 * 128];
    __shared__ float zbuf[160];
    __shared__ float zz[64];

    int g = blockIdx.x;
    int t = threadIdx.x;
    int w = t >> 6;            // wave 0..3; owns nodes n = w + 4*i
    int lane = t & 63;         // phase 1: feature f; phase 2: output pair

    float w10 = W1[lane], w11 = W1[64 + lane], w12 = W1[128 + lane], b1f = b1[lane];

    // ---- phase 1: gather+aggregate rows for this wave's 25 nodes ----
    for (int i = 0; i < 25; ++i) {
        int n = w + 4 * i;
        int node = g * NPG + n;
        int s = rowptr[node], d = cnt[node];
        float acc = 0.f;
        for (int base = 0; base < d; base += 64) {
            int m = min(64, d - base);                         // m >= 1
            int sl = (lane < m) ? slot[s + base + lane] : 0;   // coalesced
            for (int k0 = 0; k0 < m; k0 += 8) {
                float4 pre[8];
                #pragma unroll
                for (int j = 0; j < 8; ++j) {
                    int kk = min(k0 + j, m - 1);
                    pre[j] = a4[__shfl(sl, kk)];               // 8 independent loads
                }
                #pragma unroll
                for (int j = 0; j < 8; ++j) {
                    if (k0 + j < m) {                          // wave-uniform
                        float4 ar = pre[j];
                        float h = fmaxf(ar.x * w10 + ar.y * w11 + ar.z * w12 + b1f, 0.f);
                        acc += ar.w * h;
                    }
                }
            }
        }
        float4 ai = a4[node];
        float hs = fmaxf(ai.x * w10 + ai.y * w11 + ai.z * w12 + b1f, 0.f);
        aggh[n * 65 + lane] = ai.w * (acc + ai.w * hs);
    }
    // no barrier: each wave reads back only rows it wrote (same-wave lgkmcnt)

    // ---- phase 2: [25][64] @ [64][128], acc in registers, W2 streamed from L2 ----
    float2 b2v = *(const float2*)&b2[2 * lane];
    float pool0 = 0.f, pool1 = 0.f;
    {   // half A: i = 0..12
        float acc0[13], acc1[13];
        #pragma unroll
        for (int i = 0; i < 13; ++i) { acc0[i] = 0.f; acc1[i] = 0.f; }
        float2 wv0 = *(const float2*)&W2[2 * lane];
        float2 wv1 = *(const float2*)&W2[128 + 2 * lane];
        for (int f = 0; f < 64; ++f) {
            float2 wnx = (f + 2 < 64) ? *(const float2*)&W2[(f + 2) * 128 + 2 * lane] : wv0;
            #pragma unroll
            for (int i = 0; i < 13; ++i) {
                float rv = aggh[(w + 4 * i) * 65 + f];         // LDS broadcast
                acc0[i] += rv * wv0.x;
                acc1[i] += rv * wv0.y;
            }
            wv0 = wv1; wv1 = wnx;
        }
        #pragma unroll
        for (int i = 0; i < 13; ++i) {
            pool0 += fmaxf(acc0[i] + b2v.x, 0.f);
            pool1 += fmaxf(acc1[i] + b2v.y, 0.f);
        }
    }
    {   // half B: i = 13..24
        float acc0[12], acc1[12];
        #pragma unroll
        for (int i = 0; i < 12; ++i) { acc0[i] = 0.f; acc1[i] = 0.f; }
        float2 wv0 = *(const float2*)&W2[2 * lane];
        float2 wv1 = *(const float2*)&W2[128 + 2 * lane];
        for (int f = 0; f < 64; ++f) {
            float2 wnx = (f + 2 < 64) ? *(const float2*)&W2[(f + 2) * 128 + 2 * lane] : wv0;
            #pragma unroll
            for (int i = 0; i < 12; ++i) {
                float rv = aggh[(w + 4 * (13 + i)) * 65 + f];
                acc0[i] += rv * wv0.x;
                acc1[i] += rv * wv0.y;
            }
            wv0 = wv1; wv1 = wnx;
        }
        #pragma unroll
        for (int i = 0; i < 12; ++i) {
            pool0 += fmaxf(acc0[i] + b2v.x, 0.f);
            pool1 += fmaxf(acc1[i] + b2v.y, 0.f);
        }
    }

    pools[w * 128 + 2 * lane]     = pool0;
    pools[w * 128 + 2 * lane + 1] = pool1;
    __syncthreads();
    if (t < 128) {
        zbuf[t] = (pools[t] + pools[128 + t] + pools[256 + t] + pools[384 + t]) * (1.0f / NPG);
    }
    if (t < MDIM) zbuf[128 + t] = mv[g * MDIM + t];
    __syncthreads();
    if (t < 64) {
        float v = bc1[t];
        for (int k = 0; k < 160; ++k) v += zbuf[k] * Wc1[k * 64 + t];
        zz[t] = fmaxf(v, 0.f);
    }
    __syncthreads();
    if (t < NCDIM) {
        float o = bc2[t];
        #pragma unroll
        for (int k = 0; k < 64; ++k) o += zz[k] * Wc2[k * NCDIM + t];
        out[g * NCDIM + t] = o;
    }
}

extern "C" void kernel_launch(void* const* d_in, const int* in_sizes, int n_in,
                              void* d_out, int out_size, void* d_ws, size_t ws_size,
                              hipStream_t stream) {
    const float* x   = (const float*)d_in[0];
    const int*   ei  = (const int*)d_in[1];   // int64 in ref -> int32 on device
    const float* mv  = (const float*)d_in[3];
    const float* W1  = (const float*)d_in[4];
    const float* b1  = (const float*)d_in[5];
    const float* W2  = (const float*)d_in[6];
    const float* b2  = (const float*)d_in[7];
    const float* Wc1 = (const float*)d_in[8];
    const float* bc1 = (const float*)d_in[9];
    const float* Wc2 = (const float*)d_in[10];
    const float* bc2 = (const float*)d_in[11];
    float* out = (float*)d_out;

    if (ws_size < (size_t)WS_FLOATS * sizeof(float)) return;  // clean fail, no fault

    float*  ws     = (float*)d_ws;
    float4* xd4    = (float4*)(ws);             // 100000 float4
    float4* a4     = (float4*)(ws + 400000);    // 100000 float4
    int*    cnt    = (int*)(ws + 800000);
    int*    rowptr = (int*)(ws + 900000);
    int*    cursor = (int*)(ws + 1000000);
    int*    bsum   = (int*)(ws + 1099000);      // 128 ints
    int*    boff   = (int*)(ws + 1099128);      // 128 ints
    int*    slot   = (int*)(ws + 1100000);      // 3200000 ints

    hipMemsetAsync(cnt, 0, (size_t)NNODES * sizeof(int), stream);

    const int* col = ei + NEDGES;

    k_count<<<FBLKS * NPART, 256, 0, stream>>>(col, cnt);
    k_bsum <<<NB, 1024, 0, stream>>>(cnt, bsum);
    k_bscan<<<1, 128, 0, stream>>>(bsum, boff);
    k_scan2<<<NB, 1024, 0, stream>>>(cnt, boff, x, rowptr, cursor, xd4);
    k_fill <<<FBLKS * NPART, 256, 0, stream>>>(ei, cursor, slot);
    k_a    <<<(NNODES + 255) / 256, 256, 0, stream>>>(rowptr, cnt, slot, xd4, a4);
    k_fused<<<NGRAPH, 256, 0, stream>>>(rowptr, cnt, slot, a4, mv,
                                        W1, b1, W2, b2, Wc1, bc1, Wc2, bc2, out);
}

// Round 10
// 468.470 us; speedup vs baseline: 4.2128x; 1.0593x over previous
//
#include <hip/hip_runtime.h>

#define NNODES 100000
#define NEDGES 3200000
#define NGRAPH 1000
#define NPG    100
#define HALF   50          // nodes per k_fused block (half graph)
#define MDIM   32
#define NCDIM  10
#define NB     98          // ceil(NNODES/1024) scan blocks

#define NPART   8          // scatter partitions (== XCD count)
#define PSIZE   12500      // nodes per partition
#define FCHUNK  6250       // edges per chunk
#define FBLKS   (NEDGES / FCHUNK)   // 512 chunks

// ws layout (float units):
//  xd4   @ 0        : 100000 float4  (x0,x1,x2,dinv)      1.6 MB
//  a4    @ 400000   : 100000 float4  (a0,a1,a2,dinv)      1.6 MB
//  cnt   @ 800000   : 100000 int
//  rowptr@ 900000   : 100000 int
//  cursor@ 1000000  : 100000 int
//  bsum  @ 1099000  : 128 int   | boff @ 1099128 : 128 int
//  slot  @ 1100000  : 3200000 int
//  pp    @ 4300000  : 2000*128 float (half-graph pool partials)
#define WS_FLOATS 4556000   // 18.2 MB total (27.2 MB proven available in round 3)

// ---------------- K1: in-degree histogram, XCD-partitioned ----------------
__global__ __launch_bounds__(256) void k_count(const int* __restrict__ col,
                                               int* __restrict__ cnt) {
    int part  = blockIdx.x & (NPART - 1);
    int chunk = blockIdx.x >> 3;
    int base  = chunk * FCHUNK;
    int end   = base + FCHUNK;
    int clo   = part * PSIZE;
    int chi   = clo + PSIZE;
    for (int e = base + threadIdx.x; e < end; e += 256) {
        int c = col[e];
        if (c >= clo && c < chi) atomicAdd(&cnt[c], 1);
    }
}

// ---------------- K2a: per-block sums of cnt ----------------
__global__ __launch_bounds__(1024) void k_bsum(const int* __restrict__ cnt,
                                               int* __restrict__ bsum) {
    __shared__ int wsum[16];
    int b = blockIdx.x, t = threadIdx.x;
    int i = b * 1024 + t;
    int v = (i < NNODES) ? cnt[i] : 0;
    for (int off = 32; off; off >>= 1) v += __shfl_down(v, off);
    if ((t & 63) == 0) wsum[t >> 6] = v;
    __syncthreads();
    if (t < 16) {
        int s = wsum[t];
        for (int off = 8; off; off >>= 1) s += __shfl_down(s, off);
        if (t == 0) bsum[b] = s;
    }
}

// ---------------- K2b: exclusive scan of NB block sums ----------------
__global__ void k_bscan(const int* __restrict__ bsum, int* __restrict__ boff) {
    __shared__ int s[128];
    int t = threadIdx.x;
    int v = (t < NB) ? bsum[t] : 0;
    s[t] = v;
    __syncthreads();
    for (int off = 1; off < 128; off <<= 1) {
        int u = (t >= off) ? s[t - off] : 0;
        __syncthreads();
        s[t] += u;
        __syncthreads();
    }
    if (t < NB) boff[t] = s[t] - v;   // exclusive
}

// ---------------- K2c: block-local scan + offsets; also xd4/cursor ----------------
__global__ __launch_bounds__(1024) void k_scan2(const int* __restrict__ cnt,
                                                const int* __restrict__ boff,
                                                const float* __restrict__ x,
                                                int* __restrict__ rowptr,
                                                int* __restrict__ cursor,
                                                float4* __restrict__ xd4) {
    __shared__ int s[1024];
    int b = blockIdx.x, t = threadIdx.x;
    int i = b * 1024 + t;
    int c = (i < NNODES) ? cnt[i] : 0;
    s[t] = c;
    __syncthreads();
    for (int off = 1; off < 1024; off <<= 1) {
        int u = (t >= off) ? s[t - off] : 0;
        __syncthreads();
        s[t] += u;
        __syncthreads();
    }
    if (i < NNODES) {
        int excl = s[t] - c + boff[b];
        rowptr[i] = excl;
        cursor[i] = excl;
        float di = rsqrtf((float)c + 1.0f);
        xd4[i] = make_float4(x[3 * i], x[3 * i + 1], x[3 * i + 2], di);
    }
}

// ---------------- K3: XCD-partitioned scatter into CSR slots ----------------
__global__ __launch_bounds__(256) void k_fill(const int* __restrict__ ei,
                                              int* __restrict__ cursor,
                                              int* __restrict__ slot) {
    int part  = blockIdx.x & (NPART - 1);
    int chunk = blockIdx.x >> 3;
    int base  = chunk * FCHUNK;
    int end   = base + FCHUNK;
    int clo   = part * PSIZE;
    int chi   = clo + PSIZE;
    for (int e = base + threadIdx.x; e < end; e += 256) {
        int c = ei[NEDGES + e];
        if (c >= clo && c < chi) {
            int r = ei[e];
            slot[atomicAdd(&cursor[c], 1)] = r;
        }
    }
}

// ---------------- K4: a4[i]; 4-deep gather pipeline ----------------
__global__ void k_a(const int* __restrict__ rowptr, const int* __restrict__ cnt,
                    const int* __restrict__ slot, const float4* __restrict__ xd4,
                    float4* __restrict__ a4) {
    int i = blockIdx.x * blockDim.x + threadIdx.x;
    if (i >= NNODES) return;
    int s = rowptr[i], d = cnt[i];
    float ax = 0.f, ay = 0.f, az = 0.f;
    for (int k = 0; k < d; k += 4) {
        int r0 = slot[s + k];
        int r1 = slot[s + min(k + 1, d - 1)];
        int r2 = slot[s + min(k + 2, d - 1)];
        int r3 = slot[s + min(k + 3, d - 1)];
        float4 x0 = xd4[r0], x1 = xd4[r1], x2 = xd4[r2], x3 = xd4[r3];
        float u1 = (k + 1 < d) ? 1.f : 0.f;
        float u2 = (k + 2 < d) ? 1.f : 0.f;
        float u3 = (k + 3 < d) ? 1.f : 0.f;
        ax += x0.w * x0.x + u1 * x1.w * x1.x + u2 * x2.w * x2.x + u3 * x3.w * x3.x;
        ay += x0.w * x0.y + u1 * x1.w * x1.y + u2 * x2.w * x2.y + u3 * x3.w * x3.y;
        az += x0.w * x0.z + u1 * x1.w * x1.z + u2 * x2.w * x2.z + u3 * x3.w * x3.z;
    }
    float4 xi = xd4[i];
    float di = xi.w;
    a4[i] = make_float4(di * (ax + di * xi.x),
                        di * (ay + di * xi.y),
                        di * (az + di * xi.z), di);
}

// ---------------- K5: half-graph blocks; scalar-pipe gather; reg phase 2 ----------
__global__ __launch_bounds__(256, 4) void k_fused(
    const int* __restrict__ rowptr, const int* __restrict__ cnt,
    const int* __restrict__ slot, const float4* __restrict__ a4,
    const float* __restrict__ W1, const float* __restrict__ b1,
    const float* __restrict__ W2, const float* __restrict__ b2,
    float* __restrict__ pp)
{
    __shared__ float aggh[52 * 65];    // 13.5 KB (rows 50,51 are phantom pad)
    __shared__ float pools[4 * 128];

    int b = blockIdx.x;
    int g = b >> 1, half = b & 1;
    int t = threadIdx.x;
    int w = t >> 6;            // wave 0..3; owns nodes n = w + 4*i
    int lane = t & 63;         // phase 1: feature f; phase 2: output pair

    float w10 = W1[lane], w11 = W1[64 + lane], w12 = W1[128 + lane], b1f = b1[lane];
    int nn = (w < 2) ? 13 : 12;        // nodes this wave owns (50 = 13+13+12+12)

    // ---- phase 1: gather+aggregate rows; broadcast loads on the scalar pipe ----
    for (int i = 0; i < nn; ++i) {
        int n = w + 4 * i;
        int node = g * NPG + half * HALF + n;
        int s = rowptr[node], d = cnt[node];
        float acc = 0.f;
        for (int base = 0; base < d; base += 64) {
            int m = min(64, d - base);                         // m >= 1
            int sl = (lane < m) ? slot[s + base + lane] : 0;   // coalesced
            for (int k0 = 0; k0 < m; k0 += 8) {
                float4 pre[8];
                #pragma unroll
                for (int j = 0; j < 8; ++j) {
                    int kk = min(k0 + j, m - 1);
                    int rr = __builtin_amdgcn_readlane(sl, kk);  // SGPR -> s_load
                    pre[j] = a4[rr];
                }
                #pragma unroll
                for (int j = 0; j < 8; ++j) {
                    if (k0 + j < m) {                          // wave-uniform
                        float4 ar = pre[j];
                        float h = fmaxf(ar.x * w10 + ar.y * w11 + ar.z * w12 + b1f, 0.f);
                        acc += ar.w * h;
                    }
                }
            }
        }
        float4 ai = a4[node];
        float hs = fmaxf(ai.x * w10 + ai.y * w11 + ai.z * w12 + b1f, 0.f);
        aggh[n * 65 + lane] = ai.w * (acc + ai.w * hs);
    }
    // no barrier: each wave reads back only rows it wrote (same-wave lgkmcnt)

    // ---- phase 2: [<=13][64] @ [64][128], acc in registers, W2 streamed from L2 ----
    float2 b2v = *(const float2*)&b2[2 * lane];
    float acc0[13], acc1[13];
    #pragma unroll
    for (int i = 0; i < 13; ++i) { acc0[i] = 0.f; acc1[i] = 0.f; }
    {
        float2 wv0 = *(const float2*)&W2[2 * lane];
        float2 wv1 = *(const float2*)&W2[128 + 2 * lane];
        for (int f = 0; f < 64; ++f) {
            float2 wnx = (f + 2 < 64) ? *(const float2*)&W2[(f + 2) * 128 + 2 * lane] : wv0;
            #pragma unroll
            for (int i = 0; i < 13; ++i) {
                float rv = (i < nn) ? aggh[(w + 4 * i) * 65 + f] : 0.f;
                acc0[i] += rv * wv0.x;
                acc1[i] += rv * wv0.y;
            }
            wv0 = wv1; wv1 = wnx;
        }
    }
    float pool0 = 0.f, pool1 = 0.f;
    #pragma unroll
    for (int i = 0; i < 13; ++i) {
        if (i < nn) {
            pool0 += fmaxf(acc0[i] + b2v.x, 0.f);
            pool1 += fmaxf(acc1[i] + b2v.y, 0.f);
        }
    }
    pools[w * 128 + 2 * lane]     = pool0;
    pools[w * 128 + 2 * lane + 1] = pool1;
    __syncthreads();
    if (t < 128)
        pp[b * 128 + t] = pools[t] + pools[128 + t] + pools[256 + t] + pools[384 + t];
}

// ---------------- K6: merge half-graph pools + MLP head ----------------
__global__ __launch_bounds__(128) void k_head(
    const float* __restrict__ pp, const float* __restrict__ mv,
    const float* __restrict__ Wc1, const float* __restrict__ bc1,
    const float* __restrict__ Wc2, const float* __restrict__ bc2,
    float* __restrict__ out)
{
    __shared__ float zbuf[160];
    __shared__ float zz[64];
    int g = blockIdx.x;
    int t = threadIdx.x;
    if (t < 128)
        zbuf[t] = (pp[(2 * g) * 128 + t] + pp[(2 * g + 1) * 128 + t]) * (1.0f / NPG);
    if (t < MDIM) zbuf[128 + t] = mv[g * MDIM + t];
    __syncthreads();
    if (t < 64) {
        float v = bc1[t];
        for (int k = 0; k < 160; ++k) v += zbuf[k] * Wc1[k * 64 + t];
        zz[t] = fmaxf(v, 0.f);
    }
    if (t < NCDIM) {
        float o = bc2[t];
        #pragma unroll
        for (int k = 0; k < 64; ++k) o += zz[k] * Wc2[k * NCDIM + t];
        out[g * NCDIM + t] = o;
    }
}

extern "C" void kernel_launch(void* const* d_in, const int* in_sizes, int n_in,
                              void* d_out, int out_size, void* d_ws, size_t ws_size,
                              hipStream_t stream) {
    const float* x   = (const float*)d_in[0];
    const int*   ei  = (const int*)d_in[1];   // int64 in ref -> int32 on device
    const float* mv  = (const float*)d_in[3];
    const float* W1  = (const float*)d_in[4];
    const float* b1  = (const float*)d_in[5];
    const float* W2  = (const float*)d_in[6];
    const float* b2  = (const float*)d_in[7];
    const float* Wc1 = (const float*)d_in[8];
    const float* bc1 = (const float*)d_in[9];
    const float* Wc2 = (const float*)d_in[10];
    const float* bc2 = (const float*)d_in[11];
    float* out = (float*)d_out;

    if (ws_size < (size_t)WS_FLOATS * sizeof(float)) return;  // clean fail, no fault

    float*  ws     = (float*)d_ws;
    float4* xd4    = (float4*)(ws);             // 100000 float4
    float4* a4     = (float4*)(ws + 400000);    // 100000 float4
    int*    cnt    = (int*)(ws + 800000);
    int*    rowptr = (int*)(ws + 900000);
    int*    cursor = (int*)(ws + 1000000);
    int*    bsum   = (int*)(ws + 1099000);      // 128 ints
    int*    boff   = (int*)(ws + 1099128);      // 128 ints
    int*    slot   = (int*)(ws + 1100000);      // 3200000 ints
    float*  pp     = (float*)(ws + 4300000);    // 2000*128 floats

    hipMemsetAsync(cnt, 0, (size_t)NNODES * sizeof(int), stream);

    const int* col = ei + NEDGES;

    k_count<<<FBLKS * NPART, 256, 0, stream>>>(col, cnt);
    k_bsum <<<NB, 1024, 0, stream>>>(cnt, bsum);
    k_bscan<<<1, 128, 0, stream>>>(bsum, boff);
    k_scan2<<<NB, 1024, 0, stream>>>(cnt, boff, x, rowptr, cursor, xd4);
    k_fill <<<FBLKS * NPART, 256, 0, stream>>>(ei, cursor, slot);
    k_a    <<<(NNODES + 255) / 256, 256, 0, stream>>>(rowptr, cnt, slot, xd4, a4);
    k_fused<<<2 * NGRAPH, 256, 0, stream>>>(rowptr, cnt, slot, a4,
                                            W1, b1, W2, b2, pp);
    k_head <<<NGRAPH, 128, 0, stream>>>(pp, mv, Wc1, bc1, Wc2, bc2, out);
}